// Round 1
// baseline (1408.357 us; speedup 1.0000x reference)
//
#include <hip/hip_runtime.h>
#include <stdint.h>

// Problem constants
#define B_DIM 4
#define T_DIM 2048
#define D_IN  4096
#define D_OUT 16384
#define M_DIM (B_DIM * T_DIM)            // 8192 tokens
#define NW    ((size_t)D_OUT * (size_t)D_IN)  // 67108864 weights

typedef __attribute__((ext_vector_type(4))) int v4i;

// ---------------------------------------------------------------------------
// Kernel 1: per-token absmax int8 quantization of x.
// One block (256 thr) per token row of 4096 fp32. Matches reference:
// scale = max|x|/127 ; x_int = clip(round_ne(x/(scale+1e-8)), -128, 127)
// ---------------------------------------------------------------------------
__global__ __launch_bounds__(256) void act_quant_kernel(
    const float* __restrict__ x, int8_t* __restrict__ xq,
    float* __restrict__ scales) {
  const int row = blockIdx.x;
  const float4* xr = (const float4*)(x + (size_t)row * D_IN);
  float4 v[4];
  float amax = 0.f;
#pragma unroll
  for (int c = 0; c < 4; ++c) {
    v[c] = xr[c * 256 + threadIdx.x];
    amax = fmaxf(amax, fmaxf(fmaxf(fabsf(v[c].x), fabsf(v[c].y)),
                             fmaxf(fabsf(v[c].z), fabsf(v[c].w))));
  }
#pragma unroll
  for (int off = 32; off > 0; off >>= 1)
    amax = fmaxf(amax, __shfl_down(amax, off, 64));
  __shared__ float smax[4];
  const int lane = threadIdx.x & 63, wave = threadIdx.x >> 6;
  if (lane == 0) smax[wave] = amax;
  __syncthreads();
  amax = fmaxf(fmaxf(smax[0], smax[1]), fmaxf(smax[2], smax[3]));
  const float scale = amax * (1.0f / 127.0f);
  const float denom = scale + 1e-8f;
  if (threadIdx.x == 0) scales[row] = scale;
  int* outp = (int*)(xq + (size_t)row * D_IN);
#pragma unroll
  for (int c = 0; c < 4; ++c) {
    // exact IEEE division + round-to-nearest-even to bit-match jnp.round(x/d)
    int q0 = min(127, max(-128, __float2int_rn(v[c].x / denom)));
    int q1 = min(127, max(-128, __float2int_rn(v[c].y / denom)));
    int q2 = min(127, max(-128, __float2int_rn(v[c].z / denom)));
    int q3 = min(127, max(-128, __float2int_rn(v[c].w / denom)));
    outp[c * 256 + threadIdx.x] =
        (q0 & 255) | ((q1 & 255) << 8) | ((q2 & 255) << 16) | ((q3 & 255) << 24);
  }
}

// ---------------------------------------------------------------------------
// Kernel 2a: sum(|W|) in double (deterministic enough that the ternary
// threshold matches JAX's fp32 mean: flipping near-threshold weights is the
// real numerical hazard here, not the GEMM).
// ---------------------------------------------------------------------------
__global__ __launch_bounds__(256) void wabs_kernel(const float* __restrict__ w,
                                                   double* __restrict__ out) {
  const float4* w4 = (const float4*)w;
  const size_t n4 = NW / 4;
  double acc = 0.0;
  for (size_t i = (size_t)blockIdx.x * blockDim.x + threadIdx.x; i < n4;
       i += (size_t)gridDim.x * blockDim.x) {
    float4 v = w4[i];
    acc += (double)fabsf(v.x) + (double)fabsf(v.y);
    acc += (double)fabsf(v.z) + (double)fabsf(v.w);
  }
#pragma unroll
  for (int off = 32; off > 0; off >>= 1) acc += __shfl_down(acc, off, 64);
  __shared__ double ssum[4];
  const int lane = threadIdx.x & 63, wave = threadIdx.x >> 6;
  if (lane == 0) ssum[wave] = acc;
  __syncthreads();
  if (threadIdx.x == 0) atomicAdd(out, ssum[0] + ssum[1] + ssum[2] + ssum[3]);
}

// ---------------------------------------------------------------------------
// Kernel 2b: ternarize weights exactly as reference:
// t = w/(mean|w|+1e-8); Wq = sign(t) * (|t| > 0.5)  in {-1,0,+1} int8
// ---------------------------------------------------------------------------
__global__ __launch_bounds__(256) void wquant_kernel(
    const float* __restrict__ w, const double* __restrict__ sumAbs,
    int8_t* __restrict__ wq) {
  const float ws = (float)(*sumAbs / (double)NW) + 1e-8f;
  const float4* w4 = (const float4*)w;
  int* outp = (int*)wq;
  const size_t stride = (size_t)gridDim.x * blockDim.x;
  size_t i = (size_t)blockIdx.x * blockDim.x + threadIdx.x;
#pragma unroll
  for (int c = 0; c < 4; ++c, i += stride) {
    float4 v = w4[i];
    float t0 = v.x / ws, t1 = v.y / ws, t2 = v.z / ws, t3 = v.w / ws;
    int q0 = (fabsf(t0) > 0.5f) ? ((t0 > 0.f) ? 1 : -1) : 0;
    int q1 = (fabsf(t1) > 0.5f) ? ((t1 > 0.f) ? 1 : -1) : 0;
    int q2 = (fabsf(t2) > 0.5f) ? ((t2 > 0.f) ? 1 : -1) : 0;
    int q3 = (fabsf(t3) > 0.5f) ? ((t3 > 0.f) ? 1 : -1) : 0;
    outp[i] = (q0 & 255) | ((q1 & 255) << 8) | ((q2 & 255) << 16) | ((q3 & 255) << 24);
  }
}

// ---------------------------------------------------------------------------
// Kernel 3: int8 GEMM, m97 structure.
// C[m,n] = scale[m] * (sum_k xq[m,k]*wq[n,k]) + bias[n]
// 128x128 block tile, BK=64 (one 16x16x64 i8 MFMA K-step), 4 waves as 2x2,
// each wave 64x64 = 4x4 MFMAs. global_load_lds width=16 staging; XOR-swizzled
// chunk placement so frag ds_read_b128 is 2-way bank aliasing (free).
// ---------------------------------------------------------------------------
#define BM 128
#define BN 128
#define BK 64
#define KTILES (D_IN / BK)  // 64

__global__ __launch_bounds__(256) void gemm_i8_kernel(
    const int8_t* __restrict__ xq, const int8_t* __restrict__ wq,
    const float* __restrict__ scales, const float* __restrict__ bias,
    float* __restrict__ out) {
  __shared__ __align__(16) int8_t lA[BM * BK];  // 8 KB
  __shared__ __align__(16) int8_t lB[BN * BK];  // 8 KB

  const int tid = threadIdx.x;
  const int lane = tid & 63;
  const int wave = tid >> 6;
  const int wr = wave >> 1;   // wave M index (0..1)
  const int wc = wave & 1;    // wave N index (0..1)
  const int quad = lane >> 4; // 0..3 (K-chunk for frags; row-group for C)
  const int r16 = lane & 15;

  const int bm = blockIdx.y * BM;
  const int bn = blockIdx.x * BN;

  // staging: inst i covers rows i*64 + tid/4; position tid%3.. (tid&3) in row.
  // chunk swizzle: stored position p holds global chunk p ^ ((row>>1)&3)
  const int srow = tid >> 2;                   // row within 64-row half
  const int schunk = (tid & 3) ^ ((tid >> 3) & 3);
  const int8_t* gA = xq + (size_t)bm * D_IN;
  const int8_t* gB = wq + (size_t)bn * D_IN;

  // fragment read swizzle: p = quad ^ ((row>>1)&3); row%16 == r16 always
  const int fp = (quad ^ ((r16 >> 1) & 3)) * 16;

  v4i acc[4][4] = {};

  for (int kt = 0; kt < KTILES; ++kt) {
    const int k0 = kt * BK;
    __syncthreads();  // prior compute done before overwriting LDS
#pragma unroll
    for (int i = 0; i < 2; ++i) {
      const int rl = i * 64 + srow;
      const size_t goff = (size_t)rl * D_IN + k0 + schunk * 16;
      __builtin_amdgcn_global_load_lds(
          (const __attribute__((address_space(1))) void*)(gA + goff),
          (__attribute__((address_space(3))) void*)(lA + i * 4096 + tid * 16),
          16, 0, 0);
      __builtin_amdgcn_global_load_lds(
          (const __attribute__((address_space(1))) void*)(gB + goff),
          (__attribute__((address_space(3))) void*)(lB + i * 4096 + tid * 16),
          16, 0, 0);
    }
    __syncthreads();  // drains vmcnt: staged tile visible

    v4i af[4], bf[4];
#pragma unroll
    for (int i = 0; i < 4; ++i) {
      const int m = wr * 64 + i * 16 + r16;
      af[i] = *(const v4i*)(lA + m * 64 + fp);
      const int n = wc * 64 + i * 16 + r16;
      bf[i] = *(const v4i*)(lB + n * 64 + fp);
    }
#pragma unroll
    for (int i = 0; i < 4; ++i)
#pragma unroll
      for (int j = 0; j < 4; ++j)
        acc[i][j] = __builtin_amdgcn_mfma_i32_16x16x64_i8(af[i], bf[j],
                                                          acc[i][j], 0, 0, 0);
  }

  // Epilogue. C/D layout (shape-determined): col = lane&15, row = quad*4+reg
  float bs[4];
#pragma unroll
  for (int j = 0; j < 4; ++j) bs[j] = bias[bn + wc * 64 + j * 16 + r16];

#pragma unroll
  for (int i = 0; i < 4; ++i) {
#pragma unroll
    for (int reg = 0; reg < 4; ++reg) {
      const int m = bm + wr * 64 + i * 16 + quad * 4 + reg;
      const float s = scales[m];
      float* orow = out + (size_t)m * D_OUT + bn + wc * 64 + r16;
#pragma unroll
      for (int j = 0; j < 4; ++j) {
        orow[j * 16] = (float)acc[i][j][reg] * s + bs[j];
      }
    }
  }
}

// ---------------------------------------------------------------------------
extern "C" void kernel_launch(void* const* d_in, const int* in_sizes, int n_in,
                              void* d_out, int out_size, void* d_ws,
                              size_t ws_size, hipStream_t stream) {
  const float* x = (const float*)d_in[0];     // (4,2048,4096) fp32
  const float* w = (const float*)d_in[1];     // (16384,4096) fp32
  const float* bias = (const float*)d_in[2];  // (16384,) fp32
  float* out = (float*)d_out;                 // (4,2048,16384) fp32

  // workspace layout (~96 MB total)
  char* ws = (char*)d_ws;
  double* d_sum = (double*)ws;                          // 8 B @ 0
  float* d_scales = (float*)(ws + 256);                 // 32 KB @ 256
  int8_t* d_xq = (int8_t*)(ws + 33024);                 // 32 MB
  int8_t* d_wq = (int8_t*)(ws + 33024 + (size_t)M_DIM * D_IN);  // 64 MB

  // ws is poisoned 0xAA before every timed call: zero the f64 accumulator
  hipMemsetAsync(d_sum, 0, sizeof(double), stream);

  act_quant_kernel<<<M_DIM, 256, 0, stream>>>(x, d_xq, d_scales);
  wabs_kernel<<<2048, 256, 0, stream>>>(w, d_sum);
  wquant_kernel<<<16384, 256, 0, stream>>>(w, d_sum, d_wq);
  gemm_i8_kernel<<<dim3(D_OUT / BN, M_DIM / BM), 256, 0, stream>>>(
      d_xq, d_wq, d_scales, bias, out);
}